// Round 8
// baseline (13168.842 us; speedup 1.0000x reference)
//
#include <hip/hip_runtime.h>

// HighwayLayerDiscrete: 256-step recurrent highway net, batch 64, units 1024.
// Phase P = t*4+p: p0: h=lrelu(y@w_y + xproj[t]); p1/p2: h=lrelu(h@w_h[l]+b_h[l]);
// p3: y += h@w_out + b_out; out[:,t,:]=y.
//
// R8: restructured phase interior (shell = R6/R7-proven: 256 coop blocks x 512
// thr, WG(rg,cg) owns rows [8rg,8rg+8) x cols [32cg,32cg+32) over full K; sc1
// relaxed-atomic data at LLC; NO fences (R1); no cross-WG split-K (R2/R3)).
//  1. Wave-autonomous front: wave w stages only k [128w,128w+128); compute
//     reads are wave-local => NO barrier between poll/stage/compute.
//  2. Per-producer-WAVE sub-flags (flag[rg][cg][fw], plain sc1 STORE — R7's
//     32-way same-address RMW serialized at the LLC bank); consumers poll
//     their 16 flags lane-parallel (1 coalesced load), no tid0 hotspot.
//  3. Thread tile 8 rows x 4 cols x 16 k (S=64); k-quad partials combined
//     in-register via DPP quad_perm (xor1+xor2) => red depth 16, LDS total
//     58 KB (<64 KB static limit). W drops to 16 f4/thread = 64 KB/WG/phase
//     (4x less than R7), prefetched right after the q-loop => fully hidden.
//  4. Only 2 barriers/phase (around the red exchange), both after compute.
// LDS bank audit: staging writes 8 lanes/quad (inherent min); compute A-reads
// 8 distinct quads (20*s skew) + ci-broadcast; red writes 2-way (free).

constexpr int B = 64, T = 256, U = 1024, E = 512;
constexpr int BU = B * U;  // 65536

#define LRELU(v) ((v) > 0.f ? (v) : 0.2f * (v))

using f4 = float __attribute__((ext_vector_type(4)));
using ull = unsigned long long;

__device__ __forceinline__ ull llc_load64(const float* p) {
  return __hip_atomic_load((const ull*)p, __ATOMIC_RELAXED,
                           __HIP_MEMORY_SCOPE_AGENT);
}
__device__ __forceinline__ void llc_store(float* p, float v) {
  __hip_atomic_store(p, v, __ATOMIC_RELAXED, __HIP_MEMORY_SCOPE_AGENT);
}
__device__ __forceinline__ unsigned llc_flag(const unsigned* p) {
  return __hip_atomic_load(p, __ATOMIC_RELAXED, __HIP_MEMORY_SCOPE_AGENT);
}
__device__ __forceinline__ void llc_store_u(unsigned* p, unsigned v) {
  __hip_atomic_store(p, v, __ATOMIC_RELAXED, __HIP_MEMORY_SCOPE_AGENT);
}
// quad_perm DPP adds: xor1 = [1,0,3,2] = 0xB1, xor2 = [2,3,0,1] = 0x4E
__device__ __forceinline__ float dpp_xor1(float x) {
  int r = __builtin_amdgcn_update_dpp(0, __builtin_bit_cast(int, x), 0xB1, 0xF,
                                      0xF, true);
  return __builtin_bit_cast(float, r);
}
__device__ __forceinline__ float dpp_xor2(float x) {
  int r = __builtin_amdgcn_update_dpp(0, __builtin_bit_cast(int, x), 0x4E, 0xF,
                                      0xF, true);
  return __builtin_bit_cast(float, r);
}

// ---------------- init: zero 1024 flags, y0 into slot1 and ybuf ------------
__global__ void k_init(float* __restrict__ slot1, float* __restrict__ ybuf,
                       const float* __restrict__ h0,
                       unsigned* __restrict__ flags) {
  int tid = blockIdx.x * 256 + threadIdx.x;
  if (tid < 1024) flags[tid] = 0u;
  if (tid < BU) {
    float v = h0[tid & (U - 1)];
    slot1[tid] = v;
    ybuf[tid] = v;
  }
}

// ------- xproj[t*64+n][u] = emb[x[n][t]] @ w_x + b_in (R2/R3-proven) -------
__global__ __launch_bounds__(256) void k_xproj(
    const int* __restrict__ x, const float* __restrict__ emb,
    const float* __restrict__ w_x, const float* __restrict__ b_in,
    float* __restrict__ xp) {
  __shared__ float a_s[64][36];
  __shared__ float w_s[32][64];
  __shared__ int idxs[64];
  const int tid = threadIdx.x;
  const int m0 = blockIdx.x * 64;
  const int c0 = blockIdx.y * 64;
  if (tid < 64) {
    int m = m0 + tid;
    idxs[tid] = x[(m & 63) * T + (m >> 6)];  // x[n][t], row m = t*64+n
  }
  __syncthreads();
  const int rq = tid >> 4, cq = tid & 15;
  float acc[4][4] = {};
  for (int k0 = 0; k0 < E; k0 += 32) {
#pragma unroll
    for (int rep = 0; rep < 8; ++rep) {
      int e = rep * 256 + tid;
      int r = e >> 5, k = e & 31;
      a_s[r][k] = emb[(size_t)idxs[r] * E + k0 + k];
    }
#pragma unroll
    for (int rep = 0; rep < 2; ++rep) {
      int e = rep * 256 + tid;
      int kr = e >> 4, q = e & 15;
      *(float4*)&w_s[kr][4 * q] =
          *(const float4*)(w_x + (size_t)(k0 + kr) * U + c0 + 4 * q);
    }
    __syncthreads();
#pragma unroll
    for (int kc = 0; kc < 32; kc += 4) {
      float4 a4[4], w4[4];
#pragma unroll
      for (int i = 0; i < 4; ++i) a4[i] = *(const float4*)&a_s[4 * rq + i][kc];
#pragma unroll
      for (int kk = 0; kk < 4; ++kk)
        w4[kk] = *(const float4*)&w_s[kc + kk][4 * cq];
#pragma unroll
      for (int i = 0; i < 4; ++i) {
        const float av[4] = {a4[i].x, a4[i].y, a4[i].z, a4[i].w};
#pragma unroll
        for (int kk = 0; kk < 4; ++kk) {
          acc[i][0] += av[kk] * w4[kk].x;
          acc[i][1] += av[kk] * w4[kk].y;
          acc[i][2] += av[kk] * w4[kk].z;
          acc[i][3] += av[kk] * w4[kk].w;
        }
      }
    }
    __syncthreads();
  }
  const float4 bb = *(const float4*)(b_in + c0 + 4 * cq);
  const float bv[4] = {bb.x, bb.y, bb.z, bb.w};
#pragma unroll
  for (int i = 0; i < 4; ++i) {
    float4 o;
    o.x = acc[i][0] + bv[0];
    o.y = acc[i][1] + bv[1];
    o.z = acc[i][2] + bv[2];
    o.w = acc[i][3] + bv[3];
    *(float4*)(xp + (size_t)(m0 + 4 * rq + i) * U + c0 + 4 * cq) = o;
  }
}

// ---------------- sequential pipeline ----------------
// 256 WGs = 8 rg x 32 cg (XCD = cg&7, L2-affine). Wave w (0..7) owns k-range
// [128w,128w+128). Thread: s = 8w + (l&3) + 4*(l>>5) (K-slice [16s,16s+16)),
// ci = (l>>2)&7 (cols 4ci..4ci+4 local), rows all 8. A in LDS skewed
// pos-in-row = 20*(k>>4) + (k&15), pitch 1280 (injective: max 1275).
// red[g][out], g = s>>2 (16 deep after DPP quad-reduce), pitch 268.
// Flags: flag idx = rg*128 + cg*4 + fw (fw = finalize wave 0..3, rows
// {2fw,2fw+1}); consumer wave w polls [rg*128 + 16w .. +16).
__global__ __launch_bounds__(512, 1) void k_seq(
    const float* __restrict__ xp, const float* __restrict__ w_y,
    const float* __restrict__ w_h, const float* __restrict__ b_h,
    const float* __restrict__ w_out, const float* __restrict__ b_out,
    float* __restrict__ out, float* __restrict__ slots,
    float* __restrict__ ybuf, unsigned* __restrict__ flags) {
  __shared__ float a_s[8 * 1280];  // 40960 B
  __shared__ float red[16 * 268];  // 17152 B  (total 58112 B < 64 KB)
  const int tid = threadIdx.x;
  const int cg = blockIdx.x & 31, rg = blockIdx.x >> 5;
  const int w = tid >> 6, l = tid & 63;
  const int s = 8 * w + (l & 3) + 4 * (l >> 5);  // K-slice id, 0..63
  const int ci = (l >> 2) & 7;                   // local col quad, 0..7
  unsigned* fl = flags + rg * 128;

  auto wbase = [&](int P2) -> const float* {
    const int p2 = P2 & 3;
    const float* W = (p2 == 0)   ? w_y
                     : (p2 == 3) ? w_out
                                 : w_h + (size_t)(p2 - 1) * U * U;
    return W + (size_t)(16 * s) * U + 32 * cg + 4 * ci;
  };

  // W for P=0 (16 f4 = 64 VGPRs)
  f4 wreg[16];
  {
    const float* wp = wbase(0);
#pragma unroll
    for (int j = 0; j < 16; ++j) wreg[j] = *(const f4*)(wp + (size_t)j * U);
  }

  for (int P = 0; P < 4 * T; ++P) {
    const int t = P >> 2, p = P & 3;
    // ---- 1. per-wave lane-parallel poll of this wave's 16 sub-flags ----
    if (P > 0) {
      const unsigned tg = (unsigned)P;
      const unsigned* fp = fl + 16 * w + (l & 15);
      while (__any(llc_flag(fp) < tg)) __builtin_amdgcn_s_sleep(1);
      asm volatile("" ::: "memory");
    }
    // ---- 2. stage own k-range: 8 rows x 128 k (wave-local, no barrier) ----
    {
      const float* Asrc =
          slots + (size_t)((P + 1) & 1) * BU + (size_t)(8 * rg) * U + 128 * w;
      f4 v[4];
      int ai[4];
#pragma unroll
      for (int rep = 0; rep < 4; ++rep) {
        int i = 64 * rep + l;            // [0,256)
        int row = i >> 5, kq = i & 31;   // f4 index in row's 128-k range
        const float* pa = Asrc + (size_t)row * U + 4 * kq;
        ull v0 = llc_load64(pa);
        ull v1 = llc_load64(pa + 2);
        ((ull*)&v[rep])[0] = v0;
        ((ull*)&v[rep])[1] = v1;
        ai[rep] = row * 1280 + 160 * w + 20 * (kq >> 2) + 4 * (kq & 3);
      }
#pragma unroll
      for (int rep = 0; rep < 4; ++rep) *(f4*)&a_s[ai[rep]] = v[rep];
    }
    // ---- 3. compute: 8 rows x 4 cols x 16 k (A wave-local, W in regs) ----
    f4 acc[8];
#pragma unroll
    for (int r = 0; r < 8; ++r) acc[r] = (f4){0.f, 0.f, 0.f, 0.f};
    {
      const int ab = 20 * s;
#pragma unroll
      for (int q = 0; q < 4; ++q) {
        f4 a[8];
#pragma unroll
        for (int r = 0; r < 8; ++r)
          a[r] = *(const f4*)&a_s[r * 1280 + ab + 4 * q];
        const f4 w0 = wreg[4 * q], w1 = wreg[4 * q + 1];
        const f4 w2 = wreg[4 * q + 2], w3 = wreg[4 * q + 3];
#pragma unroll
        for (int r = 0; r < 8; ++r)
          acc[r] += a[r].x * w0 + a[r].y * w1 + a[r].z * w2 + a[r].w * w3;
      }
    }
    // ---- 4. W prefetch for P+1 (wreg dead; hides 64 KB L2 stream) ----
    if (P < 4 * T - 1) {
      const float* wp = wbase(P + 1);
#pragma unroll
      for (int j = 0; j < 16; ++j) wreg[j] = *(const f4*)(wp + (size_t)j * U);
    }
    // ---- 5. in-quad DPP reduce (sums 4 k-slices; all-lane symmetric) ----
#pragma unroll
    for (int r = 0; r < 8; ++r)
#pragma unroll
      for (int c2 = 0; c2 < 4; ++c2) {
        float vv = acc[r][c2];
        vv += dpp_xor1(vv);
        vv += dpp_xor2(vv);
        acc[r][c2] = vv;
      }
    // ---- 6. alpha barrier (protects red WAR vs previous finalize) ----
    __syncthreads();
    if ((l & 3) == 0) {
      const int g = 2 * w + (l >> 5);  // reduced-group id 0..15
#pragma unroll
      for (int r = 0; r < 8; ++r) *(f4*)&red[g * 268 + r * 32 + 4 * ci] = acc[r];
    }
    // ---- 7. beta barrier (red write -> read) ----
    __syncthreads();
    // ---- 8. finalize: 256 threads, sum 16 groups, bias+act, store ----
    if (tid < 256) {
      float sum = 0.f;
#pragma unroll
      for (int z = 0; z < 16; ++z) sum += red[z * 268 + tid];
      const int row = 8 * rg + (tid >> 5);
      const int u = 32 * cg + (tid & 31);
      float* slotw = slots + (size_t)(P & 1) * BU;
      if (p == 0) {
        float v = sum + xp[((size_t)t * B + row) * U + u];
        llc_store(slotw + (size_t)row * U + u, LRELU(v));
      } else if (p < 3) {
        float v = sum + b_h[(p - 1) * U + u];
        llc_store(slotw + (size_t)row * U + u, LRELU(v));
      } else {
        const size_t yi = (size_t)row * U + u;
        float yn = ybuf[yi] + sum + b_out[u];  // WG-private: plain ok
        ybuf[yi] = yn;
        out[((size_t)row * T + t) * U + u] = yn;
        llc_store(slotw + yi, yn);  // y is next p0's A
      }
    }
    // ---- 9. per-wave drain + sub-flag post (waves 0..3 = finalize waves) --
    asm volatile("" ::: "memory");
    __builtin_amdgcn_s_waitcnt(0);  // W prefetch long since issued -> ~free
    asm volatile("" ::: "memory");
    if (w < 4 && l == 0) llc_store_u(fl + cg * 4 + w, (unsigned)(P + 1));
  }
}

extern "C" void kernel_launch(void* const* d_in, const int* in_sizes, int n_in,
                              void* d_out, int out_size, void* d_ws,
                              size_t ws_size, hipStream_t stream) {
  const int* x = (const int*)d_in[0];
  const float* emb = (const float*)d_in[1];
  const float* w_y = (const float*)d_in[2];
  const float* w_x = (const float*)d_in[3];
  const float* b_in = (const float*)d_in[4];
  const float* w_h = (const float*)d_in[5];
  const float* b_h = (const float*)d_in[6];
  const float* w_out = (const float*)d_in[7];
  const float* b_out = (const float*)d_in[8];
  const float* h0 = (const float*)d_in[9];
  float* out = (float*)d_out;

  // workspace (floats): xproj | slots[2] | ybuf | flags(1024 u32)
  float* ws = (float*)d_ws;
  float* xpb = ws;                         // T*B*U
  float* slots = xpb + (size_t)T * B * U;  // 2*BU
  float* ybuf = slots + 2 * (size_t)BU;    // BU
  unsigned* flags = (unsigned*)(ybuf + (size_t)BU);  // 1024 uints

  k_init<<<256, 256, 0, stream>>>(slots + (size_t)BU, ybuf, h0, flags);
  dim3 g1(256, 16);
  k_xproj<<<g1, 256, 0, stream>>>(x, emb, w_x, b_in, xpb);

  void* args[] = {&xpb,   &w_y, &w_h,   &b_h,  &w_out,
                  &b_out, &out, &slots, &ybuf, &flags};
  hipLaunchCooperativeKernel((void*)k_seq, dim3(256), dim3(512), args, 0u,
                             stream);
}